// Round 1
// baseline (334.331 us; speedup 1.0000x reference)
//
#include <hip/hip_runtime.h>
#include <math.h>

#define NCL 21
#define CIN 256
#define HW 4096
#define PADK 24
#define NB 2

// ---------------------------------------------------------------------------
// Kernel A: f1/f2 = 1x1 conv (w @ feat + b). feat identity-resize is exact.
// f1 stored transposed+padded [n][p][24] for scalar-load columns; f2 [n][k][q].
__global__ __launch_bounds__(256) void k_feat(
    const float* __restrict__ feat, const float* __restrict__ w1,
    const float* __restrict__ b1, const float* __restrict__ w2,
    const float* __restrict__ b2, float* __restrict__ f1T,
    float* __restrict__ f2) {
  const int t = threadIdx.x;
  const int n = blockIdx.y;
  const int q = blockIdx.x * 256 + t;
  const float* fp = feat + (size_t)n * CIN * HW + q;
  float a1[NCL], a2[NCL];
#pragma unroll
  for (int k = 0; k < NCL; ++k) { a1[k] = 0.f; a2[k] = 0.f; }
  for (int c = 0; c < CIN; ++c) {
    float v = fp[(size_t)c * HW];   // coalesced vector load
#pragma unroll
    for (int k = 0; k < NCL; ++k) { // w reads are thread-uniform -> s_load
      a1[k] = fmaf(v, w1[k * CIN + c], a1[k]);
      a2[k] = fmaf(v, w2[k * CIN + c], a2[k]);
    }
  }
  float* o1 = f1T + ((size_t)n * HW + q) * PADK;
  float* o2 = f2 + (size_t)n * NCL * HW + q;
#pragma unroll
  for (int k = 0; k < NCL; ++k) {
    o1[k] = a1[k] + b1[k];
    o2[(size_t)k * HW] = a2[k] + b2[k];
  }
}

// ---------------------------------------------------------------------------
// Kernel B: out_temp = bilinear downsample of out (128x128 -> 64x64, align
// corners). Stored transposed+padded [n][p][24] (indexed by class c).
__global__ __launch_bounds__(256) void k_outr(
    const float* __restrict__ out, float* __restrict__ otT) {
  int idx = blockIdx.x * 256 + threadIdx.x;
  if (idx >= NB * NCL * HW) return;
  int p = idx & (HW - 1);
  int nk = idx >> 12;
  int i = p >> 6, j = p & 63;
  double sy = (double)i * (127.0 / 63.0);
  double sx = (double)j * (127.0 / 63.0);
  int y0 = (int)sy, x0 = (int)sx;
  float wy = (float)(sy - y0), wx = (float)(sx - x0);
  int y1 = min(y0 + 1, 127), x1 = min(x0 + 1, 127);
  const float* src = out + (size_t)nk * (128 * 128);
  float v00 = src[y0 * 128 + x0], v10 = src[y1 * 128 + x0];
  float v01 = src[y0 * 128 + x1], v11 = src[y1 * 128 + x1];
  // exact reference association order: rows over y first, then x
  float r0 = v00 * (1.f - wy) + v10 * wy;
  float r1 = v01 * (1.f - wy) + v11 * wy;
  float val = r0 * (1.f - wx) + r1 * wx;
  int n = nk / NCL, c = nk % NCL;
  otT[((size_t)n * HW + p) * PADK + c] = val;
}

// ---------------------------------------------------------------------------
// Kernel C: inv_l[n][p] = 1 / sum_q exp(S[n][p][q]), S = (f1.f2)/sqrt(21).
// Block: one n, 16 p. Threads cover q with float4 register blocking.
#define PT 16
__global__ __launch_bounds__(256) void k_stats(
    const float* __restrict__ f1T, const float* __restrict__ f2,
    float* __restrict__ invl) {
  const int t = threadIdx.x;
  const int n = blockIdx.y;
  const int pbase = blockIdx.x * PT;
  const float* f2n = f2 + (size_t)n * NCL * HW;
  const float* f1n = f1T + ((size_t)n * HW + pbase) * PADK;
  const float SCALE = 1.0f / sqrtf(21.0f);
  float sums[PT];
#pragma unroll
  for (int p = 0; p < PT; ++p) sums[p] = 0.f;
  for (int qc = 0; qc < 4; ++qc) {
    const int q0 = qc * 1024 + t * 4;
    float4 fq[NCL];
#pragma unroll
    for (int k = 0; k < NCL; ++k)
      fq[k] = *(const float4*)(f2n + (size_t)k * HW + q0);
#pragma unroll
    for (int p = 0; p < PT; ++p) {
      const float* f1p = f1n + p * PADK;  // uniform -> s_load_dwordx8
      float s0 = 0.f, s1 = 0.f, s2 = 0.f, s3 = 0.f;
#pragma unroll
      for (int k = 0; k < NCL; ++k) {
        float a = f1p[k];
        s0 = fmaf(a, fq[k].x, s0);
        s1 = fmaf(a, fq[k].y, s1);
        s2 = fmaf(a, fq[k].z, s2);
        s3 = fmaf(a, fq[k].w, s3);
      }
      sums[p] += __expf(s0 * SCALE) + __expf(s1 * SCALE) +
                 __expf(s2 * SCALE) + __expf(s3 * SCALE);
    }
  }
  __shared__ float part[4][PT];
  const int wave = t >> 6, lane = t & 63;
#pragma unroll
  for (int p = 0; p < PT; ++p) {
    float s = sums[p];
    for (int off = 32; off > 0; off >>= 1) s += __shfl_xor(s, off, 64);
    if (lane == 0) part[wave][p] = s;
  }
  __syncthreads();
  if (t < PT) {
    float l = part[0][t] + part[1][t] + part[2][t] + part[3][t];
    invl[(size_t)n * HW + pbase + t] = 1.0f / l;
  }
}

// ---------------------------------------------------------------------------
// Kernel D: corr_out[n][c][q] += sum_p otT[n][p][c] * exp(S[p][q]) * invl[p]
// p split across blocks (32 splits), fp32 atomics into zeroed output.
#define DPS 128
__global__ __launch_bounds__(256) void k_corrout(
    const float* __restrict__ f1T, const float* __restrict__ f2,
    const float* __restrict__ otT, const float* __restrict__ invl,
    float* __restrict__ corr_out) {
  const int t = threadIdx.x;
  const int n = blockIdx.z;
  const int q0 = blockIdx.x * 512 + t * 2;
  const int pbase = blockIdx.y * DPS;
  const float* f2n = f2 + (size_t)n * NCL * HW;
  const float SCALE = 1.0f / sqrtf(21.0f);
  float2 fq[NCL];
#pragma unroll
  for (int k = 0; k < NCL; ++k)
    fq[k] = *(const float2*)(f2n + (size_t)k * HW + q0);
  float2 acc[NCL];
#pragma unroll
  for (int k = 0; k < NCL; ++k) acc[k] = make_float2(0.f, 0.f);
  const float* f1p = f1T + ((size_t)n * HW + pbase) * PADK;
  const float* otp = otT + ((size_t)n * HW + pbase) * PADK;
  const float* ilp = invl + (size_t)n * HW + pbase;
  for (int p = 0; p < DPS; ++p) {
    float s0 = 0.f, s1 = 0.f;
#pragma unroll
    for (int k = 0; k < NCL; ++k) {
      float a = f1p[p * PADK + k];  // uniform -> s_load
      s0 = fmaf(a, fq[k].x, s0);
      s1 = fmaf(a, fq[k].y, s1);
    }
    float il = ilp[p];
    float w0 = __expf(s0 * SCALE) * il;
    float w1 = __expf(s1 * SCALE) * il;
#pragma unroll
    for (int c = 0; c < NCL; ++c) {
      float o = otp[p * PADK + c];  // uniform -> s_load
      acc[c].x = fmaf(o, w0, acc[c].x);
      acc[c].y = fmaf(o, w1, acc[c].y);
    }
  }
  float* co = corr_out + (size_t)n * NCL * HW + q0;
#pragma unroll
  for (int c = 0; c < NCL; ++c) {
    atomicAdd(co + (size_t)c * HW, acc[c].x);
    atomicAdd(co + (size_t)c * HW + 1, acc[c].y);
  }
}

// ---------------------------------------------------------------------------
// Kernel E: per sampled row: softmax row -> bilinear upsample 64->128 ->
// min/max normalize -> >0.5 booleans (as 1.0/0.0 floats).
__global__ __launch_bounds__(256) void k_sample(
    const float* __restrict__ f1T, const float* __restrict__ f2,
    const float* __restrict__ invl, const int* __restrict__ index,
    float* __restrict__ out0) {
  __shared__ float row[HW];
  __shared__ float redmn[4], redmx[4];
  const int t = threadIdx.x;
  const int i = blockIdx.x;
  const int n = blockIdx.y;
  int p = index[i];
  p = max(0, min(p, HW - 1));
  const float* f1p = f1T + ((size_t)n * HW + p) * PADK;  // uniform
  const float* f2n = f2 + (size_t)n * NCL * HW;
  const float il = invl[(size_t)n * HW + p];
  const float SCALE = 1.0f / sqrtf(21.0f);
  for (int j = 0; j < 16; ++j) {
    int q = t + j * 256;
    float s = 0.f;
#pragma unroll
    for (int k = 0; k < NCL; ++k)
      s = fmaf(f1p[k], f2n[(size_t)k * HW + q], s);
    row[q] = __expf(s * SCALE) * il;
  }
  __syncthreads();
  float lmn = 1e30f, lmx = -1e30f;
  for (int j = 0; j < 64; ++j) {
    int pix = t + j * 256;
    int yy = pix >> 7, xx = pix & 127;
    double sy = (double)yy * (63.0 / 127.0);
    double sx = (double)xx * (63.0 / 127.0);
    int y0 = (int)sy, x0 = (int)sx;
    float wy = (float)(sy - y0), wx = (float)(sx - x0);
    int y1 = min(y0 + 1, 63), x1 = min(x0 + 1, 63);
    float r0 = row[y0 * 64 + x0] * (1.f - wy) + row[y1 * 64 + x0] * wy;
    float r1 = row[y0 * 64 + x1] * (1.f - wy) + row[y1 * 64 + x1] * wy;
    float v = r0 * (1.f - wx) + r1 * wx;
    lmn = fminf(lmn, v);
    lmx = fmaxf(lmx, v);
  }
  for (int off = 32; off > 0; off >>= 1) {
    lmn = fminf(lmn, __shfl_xor(lmn, off, 64));
    lmx = fmaxf(lmx, __shfl_xor(lmx, off, 64));
  }
  const int wave = t >> 6, lane = t & 63;
  if (lane == 0) { redmn[wave] = lmn; redmx[wave] = lmx; }
  __syncthreads();
  float mn = fminf(fminf(redmn[0], redmn[1]), fminf(redmn[2], redmn[3]));
  float mx = fmaxf(fmaxf(redmx[0], redmx[1]), fmaxf(redmx[2], redmx[3]));
  float* dst = out0 + ((size_t)n * 128 + i) * (128 * 128);
  for (int j = 0; j < 64; ++j) {
    int pix = t + j * 256;
    int yy = pix >> 7, xx = pix & 127;
    double sy = (double)yy * (63.0 / 127.0);
    double sx = (double)xx * (63.0 / 127.0);
    int y0 = (int)sy, x0 = (int)sx;
    float wy = (float)(sy - y0), wx = (float)(sx - x0);
    int y1 = min(y0 + 1, 63), x1 = min(x0 + 1, 63);
    float r0 = row[y0 * 64 + x0] * (1.f - wy) + row[y1 * 64 + x0] * wy;
    float r1 = row[y0 * 64 + x1] * (1.f - wy) + row[y1 * 64 + x1] * wy;
    float v = r0 * (1.f - wx) + r1 * wx;
    float nrm = (v - mn) / (mx - mn);
    dst[pix] = (nrm > 0.5f) ? 1.0f : 0.0f;
  }
}

// ---------------------------------------------------------------------------
extern "C" void kernel_launch(void* const* d_in, const int* in_sizes, int n_in,
                              void* d_out, int out_size, void* d_ws,
                              size_t ws_size, hipStream_t stream) {
  (void)in_sizes; (void)n_in; (void)out_size; (void)ws_size;
  const float* feat = (const float*)d_in[0];
  const float* out  = (const float*)d_in[1];
  const float* w1   = (const float*)d_in[2];
  const float* b1   = (const float*)d_in[3];
  const float* w2   = (const float*)d_in[4];
  const float* b2   = (const float*)d_in[5];
  const int* index  = (const int*)d_in[6];

  float* ws   = (float*)d_ws;
  float* f1T  = ws;                                  // 2*4096*24 = 196608
  float* f2   = ws + 196608;                         // 2*21*4096 = 172032
  float* otT  = ws + 196608 + 172032;                // 196608
  float* invl = ws + 196608 + 172032 + 196608;       // 8192

  float* out0     = (float*)d_out;                   // 2*128*128*128
  float* corr_out = out0 + (size_t)NB * 128 * 128 * 128;  // 2*21*4096

  k_feat<<<dim3(16, 2), 256, 0, stream>>>(feat, w1, b1, w2, b2, f1T, f2);
  k_outr<<<dim3(672), 256, 0, stream>>>(out, otT);
  k_stats<<<dim3(HW / PT, 2), 256, 0, stream>>>(f1T, f2, invl);
  hipMemsetAsync(corr_out, 0, (size_t)NB * NCL * HW * sizeof(float), stream);
  k_corrout<<<dim3(8, HW / DPS, 2), 256, 0, stream>>>(f1T, f2, otT, invl,
                                                      corr_out);
  k_sample<<<dim3(128, 2), 256, 0, stream>>>(f1T, f2, invl, index, out0);
}

// Round 2
// 235.123 us; speedup vs baseline: 1.4219x; 1.4219x over previous
//
#include <hip/hip_runtime.h>
#include <math.h>

#define NCL 21
#define CIN 256
#define HW 4096
#define PADK 24
#define NB 2

static __device__ __forceinline__ float fastrcp(float x) {
  return __builtin_amdgcn_rcpf(x);
}

// ---------------------------------------------------------------------------
// Kernel A: f1/f2 = 1x1 conv (w @ feat + b). Block = 32 q-positions x 8
// c-chunks of 32; LDS reduction across chunks. Grid 256 blocks (was 32 -> the
// 120us / 1.4% occupancy problem).
#define QT 32
__global__ __launch_bounds__(256) void k_feat(
    const float* __restrict__ feat, const float* __restrict__ w1,
    const float* __restrict__ b1, const float* __restrict__ w2,
    const float* __restrict__ b2, float* __restrict__ f1T,
    float* __restrict__ f2) {
  const int t = threadIdx.x;
  const int qi = t & 31, ch = t >> 5;  // 8 chunks of 32 channels
  const int n = blockIdx.y;
  const int q = blockIdx.x * QT + qi;
  const int c0 = ch * 32;
  const float* fp = feat + ((size_t)n * CIN + c0) * HW + q;
  float a1[NCL], a2[NCL];
#pragma unroll
  for (int k = 0; k < NCL; ++k) { a1[k] = 0.f; a2[k] = 0.f; }
  for (int cc = 0; cc < 32; ++cc) {
    float v = fp[(size_t)cc * HW];  // 128B coalesced per half-wave
#pragma unroll
    for (int k = 0; k < NCL; ++k) {  // w reads thread-uniform -> s_load
      a1[k] = fmaf(v, w1[k * CIN + c0 + cc], a1[k]);
      a2[k] = fmaf(v, w2[k * CIN + c0 + cc], a2[k]);
    }
  }
  __shared__ float p1[8][QT][NCL];
  __shared__ float p2[8][QT][NCL];
#pragma unroll
  for (int k = 0; k < NCL; ++k) { p1[ch][qi][k] = a1[k]; p2[ch][qi][k] = a2[k]; }
  __syncthreads();
  for (int o = t; o < QT * NCL; o += 256) {
    int qq = o & 31, k = o >> 5;
    float s1 = b1[k], s2 = b2[k];
#pragma unroll
    for (int c = 0; c < 8; ++c) { s1 += p1[c][qq][k]; s2 += p2[c][qq][k]; }
    int qg = blockIdx.x * QT + qq;
    f1T[((size_t)n * HW + qg) * PADK + k] = s1;
    f2[((size_t)n * NCL + k) * HW + qg] = s2;
  }
}

// ---------------------------------------------------------------------------
// Kernel B: out_temp = bilinear downsample of out (128x128 -> 64x64, align
// corners). Stored transposed+padded [n][p][24].
__global__ __launch_bounds__(256) void k_outr(
    const float* __restrict__ out, float* __restrict__ otT) {
  int idx = blockIdx.x * 256 + threadIdx.x;
  if (idx >= NB * NCL * HW) return;
  int p = idx & (HW - 1);
  int nk = idx >> 12;
  int i = p >> 6, j = p & 63;
  double sy = (double)i * (127.0 / 63.0);
  double sx = (double)j * (127.0 / 63.0);
  int y0 = (int)sy, x0 = (int)sx;
  float wy = (float)(sy - y0), wx = (float)(sx - x0);
  int y1 = min(y0 + 1, 127), x1 = min(x0 + 1, 127);
  const float* src = out + (size_t)nk * (128 * 128);
  float v00 = src[y0 * 128 + x0], v10 = src[y1 * 128 + x0];
  float v01 = src[y0 * 128 + x1], v11 = src[y1 * 128 + x1];
  float r0 = v00 * (1.f - wy) + v10 * wy;
  float r1 = v01 * (1.f - wy) + v11 * wy;
  float val = r0 * (1.f - wx) + r1 * wx;
  int n = nk / NCL, c = nk % NCL;
  otT[((size_t)n * HW + p) * PADK + c] = val;
}

// ---------------------------------------------------------------------------
// Kernel T: precompute bilinear tables for the 64->128 upsample (one 128-entry
// table; y and x mappings are identical). Double math once, not per pixel.
__global__ void k_tab(float* __restrict__ wtab, int* __restrict__ itab) {
  int i = threadIdx.x;
  if (i >= 128) return;
  double s = (double)i * (63.0 / 127.0);
  int i0 = (int)s;
  wtab[i] = (float)(s - i0);
  itab[i] = i0;
}

// ---------------------------------------------------------------------------
// Kernel C: l[n][p] = sum_q exp(S[n][p][q]), S = (f1.f2)/sqrt(21).
// q split 4-ways across blocks, float atomics into zeroed l. Grid 2048 blocks.
#define PT 16
__global__ __launch_bounds__(256) void k_stats(
    const float* __restrict__ f1T, const float* __restrict__ f2,
    float* __restrict__ l) {
  const int t = threadIdx.x;
  const int n = blockIdx.z;
  const int pbase = blockIdx.x * PT;
  const int q0 = blockIdx.y * 1024 + t * 4;
  const float* f2n = f2 + (size_t)n * NCL * HW;
  const float* f1n = f1T + ((size_t)n * HW + pbase) * PADK;
  const float SCALE = 1.0f / sqrtf(21.0f);
  float4 fq[NCL];
#pragma unroll
  for (int k = 0; k < NCL; ++k)
    fq[k] = *(const float4*)(f2n + (size_t)k * HW + q0);
  float sums[PT];
#pragma unroll
  for (int p = 0; p < PT; ++p) {
    const float* f1p = f1n + p * PADK;  // uniform -> s_load
    float s0 = 0.f, s1 = 0.f, s2 = 0.f, s3 = 0.f;
#pragma unroll
    for (int k = 0; k < NCL; ++k) {
      float a = f1p[k];
      s0 = fmaf(a, fq[k].x, s0);
      s1 = fmaf(a, fq[k].y, s1);
      s2 = fmaf(a, fq[k].z, s2);
      s3 = fmaf(a, fq[k].w, s3);
    }
    sums[p] = __expf(s0 * SCALE) + __expf(s1 * SCALE) + __expf(s2 * SCALE) +
              __expf(s3 * SCALE);
  }
  __shared__ float part[4][PT];
  const int wave = t >> 6, lane = t & 63;
#pragma unroll
  for (int p = 0; p < PT; ++p) {
    float s = sums[p];
    for (int off = 32; off > 0; off >>= 1) s += __shfl_xor(s, off, 64);
    if (lane == 0) part[wave][p] = s;
  }
  __syncthreads();
  if (t < PT) {
    float tot = part[0][t] + part[1][t] + part[2][t] + part[3][t];
    atomicAdd(l + (size_t)n * HW + pbase + t, tot);
  }
}

// ---------------------------------------------------------------------------
// Kernel D: corr_out[n][c][q] += sum_p otT[n][p][c] * exp(S[p][q]) / l[p].
// p split 32-ways (atomic count unchanged vs r1); q split 16-ways for
// occupancy (1024 blocks -> 16 waves/CU). 1 q per thread.
#define DPS 128
__global__ __launch_bounds__(256) void k_corrout(
    const float* __restrict__ f1T, const float* __restrict__ f2,
    const float* __restrict__ otT, const float* __restrict__ l,
    float* __restrict__ corr_out) {
  const int t = threadIdx.x;
  const int n = blockIdx.z;
  const int q = blockIdx.x * 256 + t;
  const int pbase = blockIdx.y * DPS;
  const float* f2n = f2 + (size_t)n * NCL * HW;
  const float SCALE = 1.0f / sqrtf(21.0f);
  float fq[NCL];
#pragma unroll
  for (int k = 0; k < NCL; ++k) fq[k] = f2n[(size_t)k * HW + q];
  float acc[NCL];
#pragma unroll
  for (int k = 0; k < NCL; ++k) acc[k] = 0.f;
  const float* f1p = f1T + ((size_t)n * HW + pbase) * PADK;
  const float* otp = otT + ((size_t)n * HW + pbase) * PADK;
  const float* lp = l + (size_t)n * HW + pbase;
  for (int p = 0; p < DPS; ++p) {
    float s = 0.f;
#pragma unroll
    for (int k = 0; k < NCL; ++k)
      s = fmaf(f1p[p * PADK + k], fq[k], s);  // f1p uniform -> s_load
    float w = __expf(s * SCALE) * fastrcp(lp[p]);
#pragma unroll
    for (int c = 0; c < NCL; ++c)
      acc[c] = fmaf(otp[p * PADK + c], w, acc[c]);  // otp uniform -> s_load
  }
  float* co = corr_out + (size_t)n * NCL * HW + q;
#pragma unroll
  for (int c = 0; c < NCL; ++c) atomicAdd(co + (size_t)c * HW, acc[c]);
}

// ---------------------------------------------------------------------------
// Kernel E: per sampled row: softmax row -> bilinear upsample 64->128 (table-
// driven, float-only) -> min/max normalize -> >0.5 booleans as 1.0/0.0.
// Interpolated values cached in a 64-reg array; second pass is reg-only.
__global__ __launch_bounds__(256) void k_sample(
    const float* __restrict__ f1T, const float* __restrict__ f2,
    const float* __restrict__ l, const int* __restrict__ index,
    const float* __restrict__ wtab, const int* __restrict__ itab,
    float* __restrict__ out0) {
  __shared__ float row[HW];
  __shared__ float redmn[4], redmx[4];
  __shared__ float wt[128];
  __shared__ int it[128];
  const int t = threadIdx.x;
  const int i = blockIdx.x;
  const int n = blockIdx.y;
  if (t < 128) { wt[t] = wtab[t]; it[t] = itab[t]; }
  int p = index[i];
  p = max(0, min(p, HW - 1));
  const float* f1p = f1T + ((size_t)n * HW + p) * PADK;  // uniform
  const float* f2n = f2 + (size_t)n * NCL * HW;
  const float il = fastrcp(l[(size_t)n * HW + p]);
  const float SCALE = 1.0f / sqrtf(21.0f);
  for (int j = 0; j < 16; ++j) {
    int q = t + j * 256;
    float s = 0.f;
#pragma unroll
    for (int k = 0; k < NCL; ++k)
      s = fmaf(f1p[k], f2n[(size_t)k * HW + q], s);
    row[q] = __expf(s * SCALE) * il;
  }
  __syncthreads();
  float vv[64];
  float lmn = 1e30f, lmx = -1e30f;
  for (int j = 0; j < 64; ++j) {
    int pix = t + j * 256;
    int yy = pix >> 7, xx = pix & 127;
    int y0 = it[yy], x0 = it[xx];
    float wy = wt[yy], wx = wt[xx];
    int y1 = min(y0 + 1, 63), x1 = min(x0 + 1, 63);
    float r0 = row[y0 * 64 + x0] * (1.f - wy) + row[y1 * 64 + x0] * wy;
    float r1 = row[y0 * 64 + x1] * (1.f - wy) + row[y1 * 64 + x1] * wy;
    float v = r0 * (1.f - wx) + r1 * wx;
    vv[j] = v;
    lmn = fminf(lmn, v);
    lmx = fmaxf(lmx, v);
  }
  for (int off = 32; off > 0; off >>= 1) {
    lmn = fminf(lmn, __shfl_xor(lmn, off, 64));
    lmx = fmaxf(lmx, __shfl_xor(lmx, off, 64));
  }
  const int wave = t >> 6, lane = t & 63;
  if (lane == 0) { redmn[wave] = lmn; redmx[wave] = lmx; }
  __syncthreads();
  float mn = fminf(fminf(redmn[0], redmn[1]), fminf(redmn[2], redmn[3]));
  float mx = fmaxf(fmaxf(redmx[0], redmx[1]), fmaxf(redmx[2], redmx[3]));
  float rng = mx - mn;
  float* dst = out0 + ((size_t)n * 128 + i) * (128 * 128);
  for (int j = 0; j < 64; ++j) {
    int pix = t + j * 256;
    float nrm = (vv[j] - mn) / rng;  // exact div: matches r1-passing numerics
    dst[pix] = (nrm > 0.5f) ? 1.0f : 0.0f;
  }
}

// ---------------------------------------------------------------------------
extern "C" void kernel_launch(void* const* d_in, const int* in_sizes, int n_in,
                              void* d_out, int out_size, void* d_ws,
                              size_t ws_size, hipStream_t stream) {
  (void)in_sizes; (void)n_in; (void)out_size; (void)ws_size;
  const float* feat = (const float*)d_in[0];
  const float* out  = (const float*)d_in[1];
  const float* w1   = (const float*)d_in[2];
  const float* b1   = (const float*)d_in[3];
  const float* w2   = (const float*)d_in[4];
  const float* b2   = (const float*)d_in[5];
  const int* index  = (const int*)d_in[6];

  float* ws   = (float*)d_ws;
  float* f1T  = ws;                                   // 2*4096*24 = 196608
  float* f2   = ws + 196608;                          // 2*21*4096 = 172032
  float* otT  = ws + 196608 + 172032;                 // 196608
  float* lbuf = ws + 196608 + 172032 + 196608;        // 8192
  float* wtab = lbuf + 8192;                          // 128
  int*   itab = (int*)(wtab + 128);                   // 128

  float* out0     = (float*)d_out;                    // 2*128*128*128
  float* corr_out = out0 + (size_t)NB * 128 * 128 * 128;  // 2*21*4096

  k_feat<<<dim3(HW / QT, 2), 256, 0, stream>>>(feat, w1, b1, w2, b2, f1T, f2);
  k_outr<<<dim3(672), 256, 0, stream>>>(out, otT);
  k_tab<<<dim3(1), 128, 0, stream>>>(wtab, itab);
  hipMemsetAsync(lbuf, 0, (size_t)NB * HW * sizeof(float), stream);
  hipMemsetAsync(corr_out, 0, (size_t)NB * NCL * HW * sizeof(float), stream);
  k_stats<<<dim3(HW / PT, 4, 2), 256, 0, stream>>>(f1T, f2, lbuf);
  k_corrout<<<dim3(16, HW / DPS, 2), 256, 0, stream>>>(f1T, f2, otT, lbuf,
                                                       corr_out);
  k_sample<<<dim3(128, 2), 256, 0, stream>>>(f1T, f2, lbuf, index, wtab, itab,
                                             out0);
}

// Round 3
// 217.556 us; speedup vs baseline: 1.5368x; 1.0807x over previous
//
#include <hip/hip_runtime.h>
#include <math.h>

#define NCL 21
#define CIN 256
#define HW 4096
#define PADK 24
#define NB 2

static __device__ __forceinline__ float fastrcp(float x) {
  return __builtin_amdgcn_rcpf(x);
}

// ---------------------------------------------------------------------------
// Kernel A: f1/f2 = 1x1 conv (w @ feat + b). Block = 16 q-positions x 16
// c-chunks of 16 channels; LDS reduction across chunks. Grid 512 blocks.
#define QT 16
#define CCH 16
__global__ __launch_bounds__(256) void k_feat(
    const float* __restrict__ feat, const float* __restrict__ w1,
    const float* __restrict__ b1, const float* __restrict__ w2,
    const float* __restrict__ b2, float* __restrict__ f1T,
    float* __restrict__ f2) {
  const int t = threadIdx.x;
  const int qi = t & 15, ch = t >> 4;  // 16 chunks of 16 channels
  const int n = blockIdx.y;
  const int q = blockIdx.x * QT + qi;
  const int c0 = ch * CCH;
  const float* fp = feat + ((size_t)n * CIN + c0) * HW + q;
  float a1[NCL], a2[NCL];
#pragma unroll
  for (int k = 0; k < NCL; ++k) { a1[k] = 0.f; a2[k] = 0.f; }
#pragma unroll
  for (int cc = 0; cc < CCH; ++cc) {
    float v = fp[(size_t)cc * HW];
#pragma unroll
    for (int k = 0; k < NCL; ++k) {  // w reads thread-uniform -> s_load
      a1[k] = fmaf(v, w1[k * CIN + c0 + cc], a1[k]);
      a2[k] = fmaf(v, w2[k * CIN + c0 + cc], a2[k]);
    }
  }
  __shared__ float p1[CCH][QT][NCL];
  __shared__ float p2[CCH][QT][NCL];
#pragma unroll
  for (int k = 0; k < NCL; ++k) { p1[ch][qi][k] = a1[k]; p2[ch][qi][k] = a2[k]; }
  __syncthreads();
  for (int o = t; o < QT * NCL; o += 256) {
    int qq = o & 15, k = o >> 4;
    float s1 = b1[k], s2 = b2[k];
#pragma unroll
    for (int c = 0; c < CCH; ++c) { s1 += p1[c][qq][k]; s2 += p2[c][qq][k]; }
    int qg = blockIdx.x * QT + qq;
    f1T[((size_t)n * HW + qg) * PADK + k] = s1;
    f2[((size_t)n * NCL + k) * HW + qg] = s2;
  }
}

// ---------------------------------------------------------------------------
// Kernel B: out_temp = bilinear downsample of out (128x128 -> 64x64, align
// corners). Stored transposed+padded [n][p][24].
__global__ __launch_bounds__(256) void k_outr(
    const float* __restrict__ out, float* __restrict__ otT) {
  int idx = blockIdx.x * 256 + threadIdx.x;
  if (idx >= NB * NCL * HW) return;
  int p = idx & (HW - 1);
  int nk = idx >> 12;
  int i = p >> 6, j = p & 63;
  double sy = (double)i * (127.0 / 63.0);
  double sx = (double)j * (127.0 / 63.0);
  int y0 = (int)sy, x0 = (int)sx;
  float wy = (float)(sy - y0), wx = (float)(sx - x0);
  int y1 = min(y0 + 1, 127), x1 = min(x0 + 1, 127);
  const float* src = out + (size_t)nk * (128 * 128);
  float v00 = src[y0 * 128 + x0], v10 = src[y1 * 128 + x0];
  float v01 = src[y0 * 128 + x1], v11 = src[y1 * 128 + x1];
  float r0 = v00 * (1.f - wy) + v10 * wy;
  float r1 = v01 * (1.f - wy) + v11 * wy;
  float val = r0 * (1.f - wx) + r1 * wx;
  int n = nk / NCL, c = nk % NCL;
  otT[((size_t)n * HW + p) * PADK + c] = val;
}

// ---------------------------------------------------------------------------
// Kernel T: bilinear tables for the 64->128 upsample (y/x mappings identical).
__global__ void k_tab(float* __restrict__ wtab, int* __restrict__ itab) {
  int i = threadIdx.x;
  if (i >= 128) return;
  double s = (double)i * (63.0 / 127.0);
  int i0 = (int)s;
  wtab[i] = (float)(s - i0);
  itab[i] = i0;
}

// ---------------------------------------------------------------------------
// Kernel C: l[n][p] = sum_q exp(S[n][p][q]), S = (f1.f2)/sqrt(21).
// q split 4-ways across blocks, float atomics into zeroed l. Grid 2048 blocks.
#define PT 16
__global__ __launch_bounds__(256) void k_stats(
    const float* __restrict__ f1T, const float* __restrict__ f2,
    float* __restrict__ l) {
  const int t = threadIdx.x;
  const int n = blockIdx.z;
  const int pbase = blockIdx.x * PT;
  const int q0 = blockIdx.y * 1024 + t * 4;
  const float* f2n = f2 + (size_t)n * NCL * HW;
  const float* f1n = f1T + ((size_t)n * HW + pbase) * PADK;
  const float SCALE = 1.0f / sqrtf(21.0f);
  float4 fq[NCL];
#pragma unroll
  for (int k = 0; k < NCL; ++k)
    fq[k] = *(const float4*)(f2n + (size_t)k * HW + q0);
  float sums[PT];
#pragma unroll
  for (int p = 0; p < PT; ++p) {
    const float* f1p = f1n + p * PADK;  // uniform -> s_load
    float s0 = 0.f, s1 = 0.f, s2 = 0.f, s3 = 0.f;
#pragma unroll
    for (int k = 0; k < NCL; ++k) {
      float a = f1p[k];
      s0 = fmaf(a, fq[k].x, s0);
      s1 = fmaf(a, fq[k].y, s1);
      s2 = fmaf(a, fq[k].z, s2);
      s3 = fmaf(a, fq[k].w, s3);
    }
    sums[p] = __expf(s0 * SCALE) + __expf(s1 * SCALE) + __expf(s2 * SCALE) +
              __expf(s3 * SCALE);
  }
  __shared__ float part[4][PT];
  const int wave = t >> 6, lane = t & 63;
#pragma unroll
  for (int p = 0; p < PT; ++p) {
    float s = sums[p];
    for (int off = 32; off > 0; off >>= 1) s += __shfl_xor(s, off, 64);
    if (lane == 0) part[wave][p] = s;
  }
  __syncthreads();
  if (t < PT) {
    float tot = part[0][t] + part[1][t] + part[2][t] + part[3][t];
    atomicAdd(l + (size_t)n * HW + pbase + t, tot);
  }
}

// ---------------------------------------------------------------------------
// Kernel D: corr_out[n][c][q] += sum_p otT[n][p][c] * exp(S[p][q]) / l[p].
// p split 64-ways, q split 16-ways -> 2048 blocks (full occupancy). Dot chain
// split in two to halve the FMA dependence path.
#define DPS 64
__global__ __launch_bounds__(256) void k_corrout(
    const float* __restrict__ f1T, const float* __restrict__ f2,
    const float* __restrict__ otT, const float* __restrict__ l,
    float* __restrict__ corr_out) {
  const int t = threadIdx.x;
  const int n = blockIdx.z;
  const int q = blockIdx.x * 256 + t;
  const int pbase = blockIdx.y * DPS;
  const float* f2n = f2 + (size_t)n * NCL * HW;
  const float SCALE = 1.0f / sqrtf(21.0f);
  float fq[NCL];
#pragma unroll
  for (int k = 0; k < NCL; ++k) fq[k] = f2n[(size_t)k * HW + q];
  float acc[NCL];
#pragma unroll
  for (int k = 0; k < NCL; ++k) acc[k] = 0.f;
  const float* f1p = f1T + ((size_t)n * HW + pbase) * PADK;
  const float* otp = otT + ((size_t)n * HW + pbase) * PADK;
  const float* lp = l + (size_t)n * HW + pbase;
  for (int p = 0; p < DPS; ++p) {
    float sa = 0.f, sb = 0.f;  // two chains: latency path ~11 FMA not 21
#pragma unroll
    for (int k = 0; k < 11; ++k)
      sa = fmaf(f1p[p * PADK + k], fq[k], sa);  // f1p uniform -> s_load
#pragma unroll
    for (int k = 11; k < NCL; ++k)
      sb = fmaf(f1p[p * PADK + k], fq[k], sb);
    float w = __expf((sa + sb) * SCALE) * fastrcp(lp[p]);
#pragma unroll
    for (int c = 0; c < NCL; ++c)
      acc[c] = fmaf(otp[p * PADK + c], w, acc[c]);  // otp uniform -> s_load
  }
  float* co = corr_out + (size_t)n * NCL * HW + q;
#pragma unroll
  for (int c = 0; c < NCL; ++c) atomicAdd(co + (size_t)c * HW, acc[c]);
}

// ---------------------------------------------------------------------------
// Kernel E1: unnormalized sampled rows. The min/max normalization downstream
// is invariant to the positive per-row softmax denominator, so we skip l[]
// entirely. Rows stored in the output-0 region itself: slot (n,i) is 16384
// floats; we park the 4096-row at its start (k_norm overwrites after reading).
__global__ __launch_bounds__(256) void k_rows(
    const float* __restrict__ f1T, const float* __restrict__ f2,
    const int* __restrict__ index, float* __restrict__ out0) {
  const int t = threadIdx.x;
  const int qc = blockIdx.x;  // 0..3
  const int i = blockIdx.y;
  const int n = blockIdx.z;
  int p = index[i];
  p = max(0, min(p, HW - 1));
  const float* f1p = f1T + ((size_t)n * HW + p) * PADK;  // uniform
  const float* f2n = f2 + (size_t)n * NCL * HW;
  const float SCALE = 1.0f / sqrtf(21.0f);
  const int q0 = qc * 1024 + t * 4;
  float4 fq[NCL];
#pragma unroll
  for (int k = 0; k < NCL; ++k)
    fq[k] = *(const float4*)(f2n + (size_t)k * HW + q0);
  float s0 = 0.f, s1 = 0.f, s2 = 0.f, s3 = 0.f;
#pragma unroll
  for (int k = 0; k < NCL; ++k) {
    float a = f1p[k];
    s0 = fmaf(a, fq[k].x, s0);
    s1 = fmaf(a, fq[k].y, s1);
    s2 = fmaf(a, fq[k].z, s2);
    s3 = fmaf(a, fq[k].w, s3);
  }
  float4 r = make_float4(__expf(s0 * SCALE), __expf(s1 * SCALE),
                         __expf(s2 * SCALE), __expf(s3 * SCALE));
  *(float4*)(out0 + ((size_t)n * 128 + i) * (128 * 128) + q0) = r;
}

// ---------------------------------------------------------------------------
// Kernel E2: per sampled row: load row -> bilinear upsample 64->128 (table-
// driven) -> min/max normalize -> >0.5 booleans as 1.0/0.0 (overwrites slot).
__global__ __launch_bounds__(256) void k_norm(
    const float* __restrict__ wtab, const int* __restrict__ itab,
    float* __restrict__ out0) {
  __shared__ float row[HW];
  __shared__ float redmn[4], redmx[4];
  __shared__ float wt[128];
  __shared__ int it[128];
  const int t = threadIdx.x;
  const int i = blockIdx.x;
  const int n = blockIdx.y;
  if (t < 128) { wt[t] = wtab[t]; it[t] = itab[t]; }
  float* slot = out0 + ((size_t)n * 128 + i) * (128 * 128);
#pragma unroll
  for (int j = 0; j < 4; ++j)
    *(float4*)(row + t * 4 + j * 1024) = *(const float4*)(slot + t * 4 + j * 1024);
  __syncthreads();
  float vv[64];
  float lmn = 1e30f, lmx = -1e30f;
  for (int j = 0; j < 64; ++j) {
    int pix = t + j * 256;
    int yy = pix >> 7, xx = pix & 127;
    int y0 = it[yy], x0 = it[xx];
    float wy = wt[yy], wx = wt[xx];
    int y1 = min(y0 + 1, 63), x1 = min(x0 + 1, 63);
    float r0 = row[y0 * 64 + x0] * (1.f - wy) + row[y1 * 64 + x0] * wy;
    float r1 = row[y0 * 64 + x1] * (1.f - wy) + row[y1 * 64 + x1] * wy;
    float v = r0 * (1.f - wx) + r1 * wx;
    vv[j] = v;
    lmn = fminf(lmn, v);
    lmx = fmaxf(lmx, v);
  }
  for (int off = 32; off > 0; off >>= 1) {
    lmn = fminf(lmn, __shfl_xor(lmn, off, 64));
    lmx = fmaxf(lmx, __shfl_xor(lmx, off, 64));
  }
  const int wave = t >> 6, lane = t & 63;
  if (lane == 0) { redmn[wave] = lmn; redmx[wave] = lmx; }
  __syncthreads();
  float mn = fminf(fminf(redmn[0], redmn[1]), fminf(redmn[2], redmn[3]));
  float mx = fmaxf(fmaxf(redmx[0], redmx[1]), fmaxf(redmx[2], redmx[3]));
  float rng = mx - mn;
  for (int j = 0; j < 64; ++j) {
    int pix = t + j * 256;
    float nrm = (vv[j] - mn) / rng;
    slot[pix] = (nrm > 0.5f) ? 1.0f : 0.0f;
  }
}

// ---------------------------------------------------------------------------
extern "C" void kernel_launch(void* const* d_in, const int* in_sizes, int n_in,
                              void* d_out, int out_size, void* d_ws,
                              size_t ws_size, hipStream_t stream) {
  (void)in_sizes; (void)n_in; (void)out_size; (void)ws_size;
  const float* feat = (const float*)d_in[0];
  const float* out  = (const float*)d_in[1];
  const float* w1   = (const float*)d_in[2];
  const float* b1   = (const float*)d_in[3];
  const float* w2   = (const float*)d_in[4];
  const float* b2   = (const float*)d_in[5];
  const int* index  = (const int*)d_in[6];

  float* ws   = (float*)d_ws;
  float* f1T  = ws;                                   // 2*4096*24 = 196608
  float* f2   = ws + 196608;                          // 2*21*4096 = 172032
  float* otT  = ws + 196608 + 172032;                 // 196608
  float* lbuf = ws + 196608 + 172032 + 196608;        // 8192
  float* wtab = lbuf + 8192;                          // 128
  int*   itab = (int*)(wtab + 128);                   // 128

  float* out0     = (float*)d_out;                    // 2*128*128*128
  float* corr_out = out0 + (size_t)NB * 128 * 128 * 128;  // 2*21*4096

  k_feat<<<dim3(HW / QT, 2), 256, 0, stream>>>(feat, w1, b1, w2, b2, f1T, f2);
  k_tab<<<dim3(1), 128, 0, stream>>>(wtab, itab);
  k_outr<<<dim3(672), 256, 0, stream>>>(out, otT);
  hipMemsetAsync(lbuf, 0, (size_t)NB * HW * sizeof(float), stream);
  hipMemsetAsync(corr_out, 0, (size_t)NB * NCL * HW * sizeof(float), stream);
  k_stats<<<dim3(HW / PT, 4, 2), 256, 0, stream>>>(f1T, f2, lbuf);
  k_rows<<<dim3(4, 128, 2), 256, 0, stream>>>(f1T, f2, index, out0);
  k_corrout<<<dim3(16, HW / DPS, 2), 256, 0, stream>>>(f1T, f2, otT, lbuf,
                                                       corr_out);
  k_norm<<<dim3(128, 2), 256, 0, stream>>>(wtab, itab, out0);
}